// Round 7
// baseline (104.563 us; speedup 1.0000x reference)
//
#include <hip/hip_runtime.h>

// out[b,c,l] = sum_r x[b,r,l] * weight[idx[b,l], r, c] + bias[idx[b,l], c]
//   x:       (4, 256, 32, 32) fp32   flat (b*256 + r)*1024 + l
//   indexes: (4096,) int             j in [0,8)
//   weight:  (8, 256, 256) fp32      (j*256 + r)*256 + c
//   bias:    (8, 256) fp32
//   out:     (4, 256, 32, 32) fp32   (b*256 + c)*1024 + l
//
// R7: SINGLE kernel. Each block self-buckets: reads the full 16 KB index
// array (L2-resident), computes per-bucket counts + block-wide packed
// prefix scan (8 buckets x 16-bit lanes in 4 uints, wave shfl scan +
// cross-wave LDS), derives its (j, start) tile and builds its own 64-token
// rowtok list — no atomics, no pre-kernels, no device globals. Then the
// R6 gather-GEMM-scatter body. Removes 2 launches + 2 dispatch gaps +
// the scatter/zero critical path.

#define N_TOK   4096
#define R_MAX   256
#define C_DIM   256
#define N_J     8
#define MT      64      // tokens per GEMM block
#define NT      64      // channels per GEMM block
#define KC      32      // K chunk
#define LDA     68      // As row stride (floats)
#define LDB     68
#define NTILE_Y 72      // >= max token tiles = 64 + 7
#define TPT     16      // tokens per thread in the scan (4096/256)

__global__ __launch_bounds__(256) void fused_kernel(const float* __restrict__ x,
                                                    const int*   __restrict__ idx,
                                                    const float* __restrict__ weight,
                                                    const float* __restrict__ bias,
                                                    float*       __restrict__ out)
{
    const int t    = threadIdx.x;
    const int lane = t & 63;
    const int wav  = t >> 6;

    __shared__ unsigned wtot[4][4];      // per-wave inclusive totals (packed)
    __shared__ int      rowtok[MT];
    __shared__ float    As[2][KC][LDA];
    __shared__ float    Bs[2][KC][LDB];

    // ---- 1. my 16 indexes (coalesced int4 loads) ----
    int myj[TPT];
    {
        const int4* __restrict__ ip = (const int4*)(idx + t * TPT);
        #pragma unroll
        for (int i = 0; i < 4; ++i) {
            const int4 v = ip[i];
            myj[i*4+0] = v.x; myj[i*4+1] = v.y; myj[i*4+2] = v.z; myj[i*4+3] = v.w;
        }
    }

    // ---- 2. packed per-thread counts: bucket j -> 16-bit lane (j&1) of cnt[j>>1]
    unsigned cnt[4] = {0u,0u,0u,0u};
    #pragma unroll
    for (int i = 0; i < TPT; ++i)
        cnt[myj[i] >> 1] += 1u << ((myj[i] & 1) << 4);

    // ---- 3. block-wide scan (wave shfl inclusive scan, then cross-wave) ----
    unsigned inc[4] = {cnt[0],cnt[1],cnt[2],cnt[3]};
    #pragma unroll
    for (int d = 1; d < 64; d <<= 1) {
        #pragma unroll
        for (int q = 0; q < 4; ++q) {
            const unsigned u = __shfl_up(inc[q], d, 64);
            if (lane >= d) inc[q] += u;
        }
    }
    if (t < MT) rowtok[t] = 0;           // init padding slots (safe token 0)
    if (lane == 63) {
        #pragma unroll
        for (int q = 0; q < 4; ++q) wtot[wav][q] = inc[q];
    }
    __syncthreads();

    unsigned tot[4]  = {0u,0u,0u,0u};
    unsigned woff[4] = {0u,0u,0u,0u};
    #pragma unroll
    for (int w = 0; w < 4; ++w) {
        #pragma unroll
        for (int q = 0; q < 4; ++q) {
            const unsigned vv = wtot[w][q];
            if (w < wav) woff[q] += vv;
            tot[q] += vv;
        }
    }
    unsigned pref[4];                    // exclusive block prefix, packed
    #pragma unroll
    for (int q = 0; q < 4; ++q) pref[q] = woff[q] + inc[q] - cnt[q];

    // ---- 4. derive (j, start) for this block (uniform across block) ----
    const int v = blockIdx.y;
    int j = -1, start = 0, total = 0;
    #pragma unroll
    for (int jj = 0; jj < N_J; ++jj) {
        const int cj  = (tot[jj >> 1] >> ((jj & 1) << 4)) & 0xFFFF;
        const int ntl = (cj + MT - 1) >> 6;
        if (j < 0 && v < total + ntl) { j = jj; start = (v - total) << 6; }
        total += ntl;
    }
    if (j < 0) return;                   // uniform exit: no barrier hazard
    const int cnt_j = (tot[j >> 1] >> ((j & 1) << 4)) & 0xFFFF;
    const int rows  = min(MT, cnt_j - start);

    // ---- 5. fill rowtok for ranks [start, start+rows) ----
    {
        int r = (int)((pref[j >> 1] >> ((j & 1) << 4)) & 0xFFFF);
        #pragma unroll
        for (int i = 0; i < TPT; ++i) {
            if (myj[i] == j) {
                const int rel = r - start;
                if (rel >= 0 && rel < MT) rowtok[rel] = t * TPT + i;
                ++r;
            }
        }
    }
    __syncthreads();

    // ---- 6. GEMM: Out[64 tok x 64 c] = X[gathered] @ W_j + bias_j ----
    const int cb = blockIdx.x * NT;

    // A staging: thread t -> token row (t&63), 8 k's at base (t>>6)*8
    const int a_row = t & 63;
    const int a_kg  = (t >> 6) * 8;
    const int tokA  = rowtok[a_row];
    const float* __restrict__ xp =
        x + ((tokA >> 10) << 18) + (tokA & 1023) + (a_kg << 10);
    // B staging: thread t -> k rows (t>>4, +16), 4 channels at (t&15)*4
    const int b_k = t >> 4;
    const int b_c = (t & 15) * 4;
    const float* __restrict__ wj = weight + j * (R_MAX * C_DIM) + cb;

    // Prologue: stage chunk 0 into buffer 0
    float ra[8];
    #pragma unroll
    for (int i = 0; i < 8; ++i) ra[i] = xp[i << 10];
    float4 rb0 = *(const float4*)(wj + b_k * C_DIM + b_c);
    float4 rb1 = *(const float4*)(wj + (b_k + 16) * C_DIM + b_c);

    #pragma unroll
    for (int i = 0; i < 8; ++i) As[0][a_kg + i][a_row] = ra[i];
    *(float4*)&Bs[0][b_k][b_c]      = rb0;
    *(float4*)&Bs[0][b_k + 16][b_c] = rb1;
    __syncthreads();

    const int tx = t & 15;               // 4 channels at tx*4
    const int ty = t >> 4;               // 4 tokens at ty*4

    float4 acc0 = {0.f,0.f,0.f,0.f};
    float4 acc1 = {0.f,0.f,0.f,0.f};
    float4 acc2 = {0.f,0.f,0.f,0.f};
    float4 acc3 = {0.f,0.f,0.f,0.f};

    int p = 0;
    for (int k0 = 0; k0 < R_MAX; k0 += KC) {
        const int kn = k0 + KC;
        if (kn < R_MAX) {                // register-prefetch next chunk
            #pragma unroll
            for (int i = 0; i < 8; ++i) ra[i] = xp[(kn + i) << 10];
            rb0 = *(const float4*)(wj + (kn + b_k) * C_DIM + b_c);
            rb1 = *(const float4*)(wj + (kn + b_k + 16) * C_DIM + b_c);
        }
        #pragma unroll
        for (int kk = 0; kk < KC; ++kk) {
            const float4 av = *(const float4*)&As[p][kk][ty * 4];
            const float4 bv = *(const float4*)&Bs[p][kk][tx * 4];
            acc0.x += av.x * bv.x; acc0.y += av.x * bv.y; acc0.z += av.x * bv.z; acc0.w += av.x * bv.w;
            acc1.x += av.y * bv.x; acc1.y += av.y * bv.y; acc1.z += av.y * bv.z; acc1.w += av.y * bv.w;
            acc2.x += av.z * bv.x; acc2.y += av.z * bv.y; acc2.z += av.z * bv.z; acc2.w += av.z * bv.w;
            acc3.x += av.w * bv.x; acc3.y += av.w * bv.y; acc3.z += av.w * bv.z; acc3.w += av.w * bv.w;
        }
        if (kn < R_MAX) {
            const int q = p ^ 1;
            #pragma unroll
            for (int i = 0; i < 8; ++i) As[q][a_kg + i][a_row] = ra[i];
            *(float4*)&Bs[q][b_k][b_c]      = rb0;
            *(float4*)&Bs[q][b_k + 16][b_c] = rb1;
            __syncthreads();
            p = q;
        }
    }

    // ---- 7. Epilogue: + bias, scatter directly to out (b,c,l) ----
    const float4 bb = *(const float4*)(bias + j * C_DIM + cb + tx * 4);
    const int c0 = cb + tx * 4;
    const int r0 = ty * 4;
    const float4 accs[4] = {acc0, acc1, acc2, acc3};
    #pragma unroll
    for (int i = 0; i < 4; ++i) {
        if (r0 + i < rows) {
            const int tokO = rowtok[r0 + i];
            float* __restrict__ op =
                out + ((tokO >> 10) << 18) + (tokO & 1023) + (c0 << 10);
            op[0 << 10] = accs[i].x + bb.x;
            op[1 << 10] = accs[i].y + bb.y;
            op[2 << 10] = accs[i].z + bb.z;
            op[3 << 10] = accs[i].w + bb.w;
        }
    }
}

extern "C" void kernel_launch(void* const* d_in, const int* in_sizes, int n_in,
                              void* d_out, int out_size, void* d_ws, size_t ws_size,
                              hipStream_t stream)
{
    const float* x      = (const float*)d_in[0];
    const int*   idx    = (const int*)  d_in[1];
    const float* weight = (const float*)d_in[2];
    const float* bias   = (const float*)d_in[3];
    float*       out    = (float*)      d_out;

    fused_kernel<<<dim3(4, NTILE_Y, 1), 256, 0, stream>>>(x, idx, weight, bias, out);
}

// Round 8
// 76.296 us; speedup vs baseline: 1.3705x; 1.3705x over previous
//
#include <hip/hip_runtime.h>

// out[b,c,l] = sum_r x[b,r,l] * weight[idx[b,l], r, c] + bias[idx[b,l], c]
//   x:       (4, 256, 32, 32) fp32   flat (b*256 + r)*1024 + l
//   indexes: (4096,) int32-read      j in [0,8)
//   weight:  (8, 256, 256) fp32      (j*256 + r)*256 + c
//   bias:    (8, 256) fp32
//   out:     (4, 256, 32, 32) fp32   (b*256 + c)*1024 + l
//
// R8: redundant-compute dense MFMA. For every j, compute W_j^T @ X densely
// with bf16 16x16x32 MFMA (8x FLOPs = 4.3 GFLOP on the 2.5 PF matrix pipe),
// epilogue writes only elements where idx[l]==j. Eliminates bucketing,
// permutation gathers, transposes, LDS, and multi-kernel gaps entirely —
// every global load is 4 full cache lines per wave. 512 blocks (2 w/SIMD).
//
// Fragment layouts (gfx950, 16x16x32 bf16):
//   A[m = lane&15][k = (lane>>4)*8 + i]   (m = output row = c)
//   B[k = (lane>>4)*8 + i][n = lane&15]   (n = output col = l)
//   D[m = (lane>>4)*4 + r][n = lane&15]

#define C_DIM 256
#define KD    256

typedef __attribute__((ext_vector_type(8))) short bf16x8;
typedef __attribute__((ext_vector_type(4))) float f32x4;

__device__ inline short f2bf(float f) {
    union { float f; unsigned u; } v; v.f = f;
    return (short)((v.u + 0x7FFFu + ((v.u >> 16) & 1u)) >> 16);  // RNE
}

__global__ __launch_bounds__(256) void fused_mfma_kernel(
    const float* __restrict__ x,
    const int*   __restrict__ idx,
    const float* __restrict__ weight,
    const float* __restrict__ bias,
    float*       __restrict__ out)
{
    const int t    = threadIdx.x;
    const int lane = t & 63;
    const int wav  = t >> 6;
    const int quad = lane >> 4;
    const int li   = lane & 15;

    const int j   = blockIdx.z;
    // wave tile: 64 c x 64 l inside a 128 x 128 block tile (waves 2x2)
    const int c0  = blockIdx.x * 128 + (wav & 1) * 64;   // 4 m-tiles of 16
    const int lg0 = blockIdx.y * 128 + (wav >> 1) * 64;  // 4 n-tiles of 16
    const int b   = lg0 >> 10;                            // 128-tiles never straddle b
    const int l0  = lg0 & 1023;

    // A source: W_j[k][c], row stride C_DIM; lane -> (c = c0+mt*16+li, k = quad*8+i)
    const float* __restrict__ wp = weight + j * (KD * C_DIM) + (quad * 8) * C_DIM + c0 + li;
    // B source: x[b][k][l], row stride 1024; lane -> (k = quad*8+i, l = l0+nt*16+li)
    const float* __restrict__ xp = x + (b << 18) + ((quad * 8) << 10) + l0 + li;

    f32x4 acc[4][4];
    #pragma unroll
    for (int mt = 0; mt < 4; ++mt)
        #pragma unroll
        for (int nt = 0; nt < 4; ++nt)
            acc[mt][nt] = (f32x4){0.f, 0.f, 0.f, 0.f};

    for (int kc = 0; kc < KD; kc += 32) {
        bf16x8 af[4], bfr[4];
        #pragma unroll
        for (int mt = 0; mt < 4; ++mt) {
            const float* __restrict__ p = wp + kc * C_DIM + mt * 16;
            #pragma unroll
            for (int i = 0; i < 8; ++i) af[mt][i] = f2bf(p[i * C_DIM]);
        }
        #pragma unroll
        for (int nt = 0; nt < 4; ++nt) {
            const float* __restrict__ p = xp + (kc << 10) + nt * 16;
            #pragma unroll
            for (int i = 0; i < 8; ++i) bfr[nt][i] = f2bf(p[i << 10]);
        }
        #pragma unroll
        for (int mt = 0; mt < 4; ++mt)
            #pragma unroll
            for (int nt = 0; nt < 4; ++nt)
                acc[mt][nt] = __builtin_amdgcn_mfma_f32_16x16x32_bf16(
                    af[mt], bfr[nt], acc[mt][nt], 0, 0, 0);
    }

    // Epilogue: lane owns D rows c = c0+mt*16+quad*4+r, col l = lg0+nt*16+li.
    // Keep only elements whose token selects this j; add bias; 4 KB-strided
    // masked stores (~1/8 lanes active; all 8 j-blocks for a tile share an
    // XCD residue so L2 merges the partial lines).
    #pragma unroll
    for (int mt = 0; mt < 4; ++mt) {
        const int cb = c0 + mt * 16 + quad * 4;
        const float4 bb = *(const float4*)(bias + j * C_DIM + cb);  // wave-quad uniform
        #pragma unroll
        for (int nt = 0; nt < 4; ++nt) {
            const int lg = lg0 + nt * 16 + li;
            if (idx[lg] != j) continue;          // per-lane predicate
            float* __restrict__ op = out + (b << 18) + (cb << 10) + (lg & 1023);
            op[0 << 10] = acc[mt][nt][0] + bb.x;
            op[1 << 10] = acc[mt][nt][1] + bb.y;
            op[2 << 10] = acc[mt][nt][2] + bb.z;
            op[3 << 10] = acc[mt][nt][3] + bb.w;
        }
    }
}

extern "C" void kernel_launch(void* const* d_in, const int* in_sizes, int n_in,
                              void* d_out, int out_size, void* d_ws, size_t ws_size,
                              hipStream_t stream)
{
    const float* x      = (const float*)d_in[0];
    const int*   idx    = (const int*)  d_in[1];
    const float* weight = (const float*)d_in[2];
    const float* bias   = (const float*)d_in[3];
    float*       out    = (float*)      d_out;

    // grid: (2 c-tiles, 32 l-tiles, 8 j) = 512 blocks; j slowest so the 8
    // j-blocks of one (c,l) tile land on the same XCD residue (id diff = 64).
    fused_mfma_kernel<<<dim3(2, 32, 8), 256, 0, stream>>>(x, idx, weight, bias, out);
}